// Round 4
// baseline (283.549 us; speedup 1.0000x reference)
//
#include <hip/hip_runtime.h>
#include <math.h>

#define N_PTS 8192
#define TPB 256
// RPB=1: one row per block, grid=8192. With grid=2048 (RPB=4) all blocks were
// co-resident and marched through pass A (VALU-bound) then pass B (HBM-bound)
// in lockstep -> phases serialized chip-wide. 4+ cohorts pipeline A against B.
// (RPB=8 measured -19us in R1: VGPR cliff. RPB=4 was 274.75us total.)

// constants
#define C_LAMBDA   2.5f
#define C_REPEL    0.15f
#define C_EPS      0.1f
#define C_NORM_EPS 1e-8f
#define C_TAUW     0.3f
#define C_TWO_PI   6.28318530717958647692f
#define C_NEG_L_LOG2E (-3.60673760222240625f)   // -2.5 * log2(e)
#define C_Q_DELTA  1e-16f   // rsqrt guard: q==0 (diagonal) stays finite

typedef float vf4 __attribute__((ext_vector_type(4)));

__device__ __forceinline__ float fast_exp2(float x) {
#if __has_builtin(__builtin_amdgcn_exp2f)
    return __builtin_amdgcn_exp2f(x);
#else
    return exp2f(x);
#endif
}
__device__ __forceinline__ float fast_rsqrt(float x) {
#if __has_builtin(__builtin_amdgcn_rsqf)
    return __builtin_amdgcn_rsqf(x);
#else
    return rsqrtf(x);
#endif
}
__device__ __forceinline__ float fast_log2(float x) {
#if __has_builtin(__builtin_amdgcn_logf)
    return __builtin_amdgcn_logf(x);   // v_log_f32 = log2
#else
    return log2f(x);
#endif
}

__device__ __forceinline__ float wave_reduce_sum(float v) {
    #pragma unroll
    for (int off = 32; off > 0; off >>= 1)
        v += __shfl_down(v, off, 64);
    return v;
}

// Pack j-stream: pk[j] = {theta, tau, cos, sin}; pk2[j] = {theta, tau}
__global__ void pack_kernel(const float* __restrict__ theta,
                            const float* __restrict__ tau,
                            float4* __restrict__ pk,
                            float2* __restrict__ pk2) {
    int i = blockIdx.x * blockDim.x + threadIdx.x;
    float t = theta[i];
    float u = tau[i];
    pk[i]  = make_float4(t, u, cosf(t), sinf(t));
    pk2[i] = make_float2(t, u);
}

// Fused, one row per block:
//   pass A = row reductions (theta_out, tau_out, invsum)  [VALU/trans-bound]
//   pass B = normalized attn row writeback (float4 stores) [HBM-write-bound]
// Small blocks + grid 8192 -> multiple cohorts resident -> A of later cohorts
// overlaps B of earlier cohorts chip-wide.
__global__ __launch_bounds__(TPB) void fused_kernel(
    const float4* __restrict__ pk,
    const float4* __restrict__ pq,   // (float4*)pk2: {th(2m),ta(2m),th(2m+1),ta(2m+1)}
    float* __restrict__ out)         // [theta_out(N) | tau_out(N) | attn(N*N)]
{
    const int tid = threadIdx.x;
    const int row = blockIdx.x;

    float4 prow = pk[row];           // wave-uniform broadcast load
    const float th_i = prow.x, ta_i = prow.y, c_i = prow.z, s_i = prow.w;

    float a_sum = 0.f, a_x = 0.f, a_y = 0.f, a_t = 0.f, rp_x = 0.f, rp_y = 0.f;

    // ---- pass A: j-sweep; compiler-scheduled loads ----
    // diagonal flows through (score=1 at j==i, repulsion self-term is exactly 0
    // because dx=dy=0 and rsqrt stays finite via C_Q_DELTA); the attention
    // self-contribution is subtracted in the finalize step.
    #pragma unroll 4
    for (int k = 0; k < N_PTS / TPB; ++k) {
        float4 cur = pk[tid + k * TPB];
        float ad    = fabsf(th_i - cur.x);
        float dth   = fminf(ad, C_TWO_PI - ad);
        float t     = fmaf(fabsf(ta_i - cur.y), C_TAUW, dth);
        float score = fast_exp2(t * C_NEG_L_LOG2E);
        a_sum += score;
        a_x    = fmaf(score, cur.z, a_x);
        a_y    = fmaf(score, cur.w, a_y);
        a_t    = fmaf(score, cur.y, a_t);

        float d   = dth + C_EPS;
        float dx  = c_i - cur.z;
        float dy  = s_i - cur.w;
        float q   = fmaf(dx, dx, dy * dy);
        float d2  = d * d;
        // 1/(d^2 * (sqrt(q)+1e-8)) ~= rsqrt((q + delta) * d^4): one trans op
        // (trans ops measured ~15 cyc/wave64 on gfx950 -> minimize count).
        float inv = fast_rsqrt((q + C_Q_DELTA) * (d2 * d2));
        rp_x = fmaf(inv, dx, rp_x);
        rp_y = fmaf(inv, dy, rp_y);
    }

    __shared__ float red[6][TPB / 64];
    __shared__ float l2s;
    const int wave = tid >> 6;
    const int lane = tid & 63;
    {
        float v0 = wave_reduce_sum(a_sum);
        float v1 = wave_reduce_sum(a_x);
        float v2 = wave_reduce_sum(a_y);
        float v3 = wave_reduce_sum(a_t);
        float v4 = wave_reduce_sum(rp_x);
        float v5 = wave_reduce_sum(rp_y);
        if (lane == 0) {
            red[0][wave] = v0; red[1][wave] = v1; red[2][wave] = v2;
            red[3][wave] = v3; red[4][wave] = v4; red[5][wave] = v5;
        }
    }
    __syncthreads();

    if (tid == 0) {
        float s = 0.f, x = 0.f, y = 0.f, t = 0.f, rx = 0.f, ry = 0.f;
        #pragma unroll
        for (int w = 0; w < TPB / 64; ++w) {
            s  += red[0][w]; x  += red[1][w]; y  += red[2][w];
            t  += red[3][w]; rx += red[4][w]; ry += red[5][w];
        }
        // subtract the j==i attention self-contribution (score == 1)
        s -= 1.0f;
        x -= c_i;
        y -= s_i;
        t -= ta_i;
        float invr = 1.0f / s;
        float fx = fmaf(x, invr, C_REPEL * rx);
        float fy = fmaf(y, invr, C_REPEL * ry);
        out[row]         = atan2f(fy, fx);   // theta_out
        out[N_PTS + row] = t * invr;         // tau_out
        l2s = fast_log2(invr);               // fold normalization into exp2
    }
    __syncthreads();

    // ---- pass B: write normalized attn row, 4 j's per thread, float4 stores ----
    const float l2 = l2s;
    float* __restrict__ rowp = out + 2 * N_PTS + (size_t)row * N_PTS;

    #pragma unroll 2
    for (int k = 0; k < N_PTS / (TPB * 4); ++k) {
        const int base = tid + k * TPB;       // pair-of-float2 quad index
        float4 f1 = pq[2 * base];             // j0, j0+1
        float4 f2 = pq[2 * base + 1];         // j0+2, j0+3
        const int j0 = 4 * base;

        float ad0  = fabsf(th_i - f1.x);
        float dth0 = fminf(ad0, C_TWO_PI - ad0);
        float t0   = fmaf(fabsf(ta_i - f1.y), C_TAUW, dth0);
        float v0   = fast_exp2(fmaf(t0, C_NEG_L_LOG2E, l2));

        float ad1  = fabsf(th_i - f1.z);
        float dth1 = fminf(ad1, C_TWO_PI - ad1);
        float t1   = fmaf(fabsf(ta_i - f1.w), C_TAUW, dth1);
        float v1   = fast_exp2(fmaf(t1, C_NEG_L_LOG2E, l2));

        float ad2  = fabsf(th_i - f2.x);
        float dth2 = fminf(ad2, C_TWO_PI - ad2);
        float t2   = fmaf(fabsf(ta_i - f2.y), C_TAUW, dth2);
        float v2   = fast_exp2(fmaf(t2, C_NEG_L_LOG2E, l2));

        float ad3  = fabsf(th_i - f2.z);
        float dth3 = fminf(ad3, C_TWO_PI - ad3);
        float t3   = fmaf(fabsf(ta_i - f2.w), C_TAUW, dth3);
        float v3   = fast_exp2(fmaf(t3, C_NEG_L_LOG2E, l2));

        vf4 o = {v0, v1, v2, v3};
        *(vf4*)(rowp + j0) = o;
    }

    // diagonal: overwrite attn[row][row] = 0 after all row stores
    __syncthreads();
    if (tid == 0) rowp[row] = 0.0f;
}

extern "C" void kernel_launch(void* const* d_in, const int* in_sizes, int n_in,
                              void* d_out, int out_size, void* d_ws, size_t ws_size,
                              hipStream_t stream) {
    const float* theta = (const float*)d_in[0];
    const float* tau   = (const float*)d_in[1];

    float4* pk  = (float4*)d_ws;                          // 128 KB
    float2* pk2 = (float2*)((char*)d_ws + 128 * 1024);    //  64 KB
    float*  out = (float*)d_out;

    pack_kernel<<<N_PTS / 256, 256, 0, stream>>>(theta, tau, pk, pk2);
    fused_kernel<<<N_PTS, TPB, 0, stream>>>(pk, (const float4*)pk2, out);
}